// Round 1
// baseline (154.141 us; speedup 1.0000x reference)
//
#include <hip/hip_runtime.h>

// BinaryConv2dSkip1x1 forward, MI355X.
// out = RPReLU( conv3x3( sign(x+mb), sf*sign(w), pad=1 ) ) + conv1x1(x, skip_w) + skip_b
//
// Binary conv via 64-bit sign words + popcount:
//   dot_tap(o) = 64 - 2*popcount(xword ^ wword[o][tap])
// Zero-pad handled by storing OOB words = 0 (all "+1") and adding a precomputed
// per-(o, edge-pattern) correction  -sf*sum_{OOB taps} colsum[o][tap]  before PReLU.

#define CIN   64
#define COUT  64
#define IMG_H 256
#define IMG_W 256
#define TW 64
#define TH 8
#define BLOCK (TW*TH/ (TH) * TH)   // 512 (documentational; literal used below)

// ---------------- prep kernel: one block, 576 threads (o = tid/9, tap = tid%9) ---------
__global__ void bq_prep_kernel(const float* __restrict__ weight,   // [64][64][3][3]
                               const float* __restrict__ pr_bias0, // [64]
                               const float* __restrict__ prelu_w,  // [64]
                               const float* __restrict__ pr_bias1, // [64]
                               const float* __restrict__ skip_b,   // [64]
                               unsigned long long* __restrict__ wwords, // [64*9]
                               float* __restrict__ cA, float* __restrict__ cS,
                               float* __restrict__ aP, float* __restrict__ cB,
                               float* __restrict__ table /* [64*9] */) {
    __shared__ float sabs_l[576];
    __shared__ int   colsum_l[576];
    int tid = threadIdx.x;
    int o = tid / 9, t = tid % 9;
    unsigned long long word = 0ull;
    float sabs = 0.f;
    #pragma unroll 8
    for (int c = 0; c < 64; ++c) {
        float wv = weight[(o*64 + c)*9 + t];
        sabs += fabsf(wv);
        if (wv < 0.f) word |= (1ull << c);
    }
    wwords[o*9 + t] = word;
    sabs_l[tid]   = sabs;
    colsum_l[tid] = 64 - 2*(int)__popcll(word);   // sum_c sign'(w[o,c,t])
    __syncthreads();
    if (t == 0) {
        float s = 0.f;
        #pragma unroll
        for (int k = 0; k < 9; ++k) s += sabs_l[o*9 + k];
        float sf = s / 576.f;
        cA[o] = sf*576.f + pr_bias0[o];
        cS[o] = 2.f*sf;
        aP[o] = prelu_w[o];
        cB[o] = pr_bias1[o] + skip_b[o];
        #pragma unroll
        for (int p = 0; p < 9; ++p) {
            int pr = p/3, pc = p%3;
            int srow = 0;
            #pragma unroll
            for (int tt = 0; tt < 9; ++tt) {
                int dh = tt/3 - 1, dw = tt%3 - 1;
                bool oob = (pr==1 && dh==-1) || (pr==2 && dh==1) ||
                           (pc==1 && dw==-1) || (pc==2 && dw==1);
                if (oob) srow += colsum_l[o*9 + tt];
            }
            table[o*9 + p] = -sf * (float)srow;
        }
    }
}

// ---------------- main fused kernel: 512 threads, tile 64x8, 1 pixel/thread -----------
__global__ __launch_bounds__(512, 4)
void bq_main_kernel(const float* __restrict__ x,      // [8][64][256][256]
                    const float* __restrict__ mb,     // [64] move0_bias
                    const float* __restrict__ skipw,  // [64][64]
                    const unsigned long long* __restrict__ wwords, // [64*9]
                    const float* __restrict__ cA_g, const float* __restrict__ cS_g,
                    const float* __restrict__ aP_g, const float* __restrict__ cB_g,
                    const float* __restrict__ table_g, // [64*9]
                    float* __restrict__ out) {
    __shared__ unsigned long long pack[TH+2][TW+2];   // sign words, tile + halo
    __shared__ float tbl[576];

    const int tid = threadIdx.x;
    const int tw = tid & 63, th = tid >> 6;
    const int bxp = blockIdx.x;        // 0..3
    const int byp = blockIdx.y;        // 0..31
    const int b   = blockIdx.z;        // 0..7
    const int w0 = bxp*TW + tw;
    const int h0 = byp*TH + th;
    const int pixoff = h0*IMG_W + w0;

    // edge-correction table -> LDS
    for (int i = tid; i < 576; i += 512) tbl[i] = table_g[i];

    const float* xb = x + ((size_t)b * CIN) * (IMG_H*IMG_W);

    // Phase A: interior pixel — load all 64 channels (kept in regs for skip conv),
    // pack sign bits of (x + mb).
    float v[64];
    unsigned int wlo = 0u, whi = 0u;
    #pragma unroll
    for (int c = 0; c < 64; ++c) {
        float xv = xb[c*(IMG_H*IMG_W) + pixoff];
        v[c] = xv;
        unsigned int u = __float_as_uint(xv + mb[c]) >> 31;   // 1 iff negative
        if (c < 32) wlo |= u << c; else whi |= u << (c-32);
    }
    pack[th+1][tw+1] = ((unsigned long long)whi << 32) | wlo;

    // Phase A2: halo sign words. 148 halo pixels * 2 half-words = 296 jobs.
    if (tid < 296) {
        int j = tid >> 1, half = tid & 1;
        int rr, cc;
        if (j < 66)       { rr = 0;       cc = j;       }
        else if (j < 132) { rr = TH+1;    cc = j - 66;  }
        else if (j < 140) { rr = j - 131; cc = 0;       }   // rr = 1..8
        else              { rr = j - 139; cc = TW+1;    }   // rr = 1..8
        int hg = byp*TH + rr - 1;
        int wg = bxp*TW + cc - 1;
        unsigned int wword = 0u;
        if (hg >= 0 && hg < IMG_H && wg >= 0 && wg < IMG_W) {
            int po = hg*IMG_W + wg;
            #pragma unroll
            for (int k = 0; k < 32; ++k) {
                int c = half*32 + k;
                float xv = xb[c*(IMG_H*IMG_W) + po];
                unsigned int u = __float_as_uint(xv + mb[c]) >> 31;
                wword |= u << k;
            }
        }
        ((unsigned int*)&pack[rr][cc])[half] = wword;   // little-endian halves
    }
    __syncthreads();

    // Phase C: per output channel — popcount conv + fp32 skip conv + RPReLU.
    const int pr  = (h0 == 0) ? 1 : ((h0 == IMG_H-1) ? 2 : 0);
    const int pcc = (w0 == 0) ? 1 : ((w0 == IMG_W-1) ? 2 : 0);
    const int pat = pr*3 + pcc;

    unsigned long long W[9];
    #pragma unroll
    for (int t = 0; t < 9; ++t) {
        W[t] = pack[th + t/3][tw + t%3];
    }

    const float4* sw4 = (const float4*)skipw;
    float* outp = out + ((size_t)b * COUT) * (IMG_H*IMG_W) + pixoff;

    #pragma unroll 1
    for (int o = 0; o < COUT; ++o) {
        // binary conv popcount accumulate
        unsigned int S = 0;
        #pragma unroll
        for (int t = 0; t < 9; ++t) {
            S += (unsigned int)__popcll(W[t] ^ wwords[o*9 + t]);
        }
        // fp32 1x1 skip conv (weights uniform across wave -> scalar/broadcast loads)
        float sacc = 0.f;
        #pragma unroll
        for (int k = 0; k < 16; ++k) {
            float4 wv = sw4[o*16 + k];
            sacc = fmaf(wv.x, v[4*k+0], sacc);
            sacc = fmaf(wv.y, v[4*k+1], sacc);
            sacc = fmaf(wv.z, v[4*k+2], sacc);
            sacc = fmaf(wv.w, v[4*k+3], sacc);
        }
        float tval = cA_g[o] - cS_g[o]*(float)S + tbl[o*9 + pat];
        float t2 = fmaxf(tval, 0.f) + aP_g[o]*fminf(tval, 0.f);
        outp[o*(IMG_H*IMG_W)] = t2 + cB_g[o] + sacc;
    }
}

extern "C" void kernel_launch(void* const* d_in, const int* in_sizes, int n_in,
                              void* d_out, int out_size, void* d_ws, size_t ws_size,
                              hipStream_t stream) {
    const float* x      = (const float*)d_in[0];
    const float* mb     = (const float*)d_in[1];
    const float* weight = (const float*)d_in[2];
    const float* pb0    = (const float*)d_in[3];
    const float* pw     = (const float*)d_in[4];
    const float* pb1    = (const float*)d_in[5];
    const float* skw    = (const float*)d_in[6];
    const float* skb    = (const float*)d_in[7];
    float* out = (float*)d_out;

    char* ws = (char*)d_ws;
    unsigned long long* wwords = (unsigned long long*)ws;   // 4608 B
    float* cA    = (float*)(ws + 4608);
    float* cS    = (float*)(ws + 4864);
    float* aP    = (float*)(ws + 5120);
    float* cB    = (float*)(ws + 5376);
    float* table = (float*)(ws + 5632);                      // 2304 B (total 7936)

    hipLaunchKernelGGL(bq_prep_kernel, dim3(1), dim3(576), 0, stream,
                       weight, pb0, pw, pb1, skb, wwords, cA, cS, aP, cB, table);
    hipLaunchKernelGGL(bq_main_kernel, dim3(4, 32, 8), dim3(512), 0, stream,
                       x, mb, skw, wwords, cA, cS, aP, cB, table, out);
}

// Round 3
// 118.008 us; speedup vs baseline: 1.3062x; 1.3062x over previous
//
#include <hip/hip_runtime.h>

// BinaryConv2dSkip1x1 forward, MI355X.
// out = RPReLU( conv3x3( sign(x+mb), sf*sign(w), pad=1 ) ) + conv1x1(x, skip_w) + skip_b
//
// Binary conv: 64-bit sign words + popcount (integer exact).
// Skip 1x1 conv: bf16 MFMA (mfma_f32_16x16x32_bf16), 64(Cout)x64(px)x64(Cin)
// per wave-row, overlapping the MFMA pipe with the VALU popcount work.

#define CIN   64
#define COUT  64
#define IMG_H 256
#define IMG_W 256
#define TW 64
#define TH 8
#define HW (IMG_H*IMG_W)

typedef __bf16 bf16x8 __attribute__((ext_vector_type(8)));
typedef float f32x4 __attribute__((ext_vector_type(4)));

__device__ __forceinline__ unsigned short f2bf(float f) {
    return __builtin_bit_cast(unsigned short, (__bf16)f);
}

__device__ __forceinline__ void lds_fence() {
    // Order same-wave LDS write -> read: drain DS queue before dependent reads.
    asm volatile("s_waitcnt lgkmcnt(0)" ::: "memory");
}

// ---------------- prep kernel: one block, 576 threads (o = tid/9, tap = tid%9) ---------
__global__ void bq_prep_kernel(const float* __restrict__ weight,   // [64][64][3][3]
                               const float* __restrict__ pr_bias0, // [64]
                               const float* __restrict__ prelu_w,  // [64]
                               const float* __restrict__ pr_bias1, // [64]
                               const float* __restrict__ skip_b,   // [64]
                               unsigned long long* __restrict__ wwords, // [64*9]
                               float* __restrict__ cA, float* __restrict__ cS,
                               float* __restrict__ aP, float* __restrict__ cB,
                               float* __restrict__ table /* [64*9] */) {
    __shared__ float sabs_l[576];
    __shared__ int   colsum_l[576];
    int tid = threadIdx.x;
    int o = tid / 9, t = tid % 9;
    unsigned long long word = 0ull;
    float sabs = 0.f;
    #pragma unroll 8
    for (int c = 0; c < 64; ++c) {
        float wv = weight[(o*64 + c)*9 + t];
        sabs += fabsf(wv);
        if (wv < 0.f) word |= (1ull << c);
    }
    wwords[o*9 + t] = word;
    sabs_l[tid]   = sabs;
    colsum_l[tid] = 64 - 2*(int)__popcll(word);   // sum_c sign'(w[o,c,t])
    __syncthreads();
    if (t == 0) {
        float s = 0.f;
        #pragma unroll
        for (int k = 0; k < 9; ++k) s += sabs_l[o*9 + k];
        float sf = s / 576.f;
        cA[o] = sf*576.f + pr_bias0[o];
        cS[o] = 2.f*sf;
        aP[o] = prelu_w[o];
        cB[o] = pr_bias1[o] + skip_b[o];
        #pragma unroll
        for (int p = 0; p < 9; ++p) {
            int pr = p/3, pc = p%3;
            int srow = 0;
            #pragma unroll
            for (int tt = 0; tt < 9; ++tt) {
                int dh = tt/3 - 1, dw = tt%3 - 1;
                bool oob = (pr==1 && dh==-1) || (pr==2 && dh==1) ||
                           (pc==1 && dw==-1) || (pc==2 && dw==1);
                if (oob) srow += colsum_l[o*9 + tt];
            }
            table[o*9 + p] = -sf * (float)srow;
        }
    }
}

// ---------------- main fused kernel: 512 threads, tile 64x8, 1 pixel/thread -----------
__global__ __launch_bounds__(512, 4)
void bq_main_kernel(const float* __restrict__ x,      // [8][64][256][256]
                    const float* __restrict__ mb,     // [64] move0_bias
                    const float* __restrict__ skipw,  // [64][64]
                    const unsigned long long* __restrict__ wwords, // [64*9]
                    const float* __restrict__ cA_g, const float* __restrict__ cS_g,
                    const float* __restrict__ aP_g, const float* __restrict__ cB_g,
                    const float* __restrict__ table_g, // [64*9]
                    float* __restrict__ out) {
    __shared__ unsigned long long pack[TH+2][TW+2];            // 5280 B
    __shared__ float tbl[576];                                  // 2304 B
    __shared__ __align__(16) unsigned short A_lds[COUT*72];     // 9216 B, [o][64+8pad]
    __shared__ __align__(16) unsigned short wbuf[TH][2560];     // 40960 B (5120/wave)

    const int tid = threadIdx.x;
    const int tw = tid & 63, th = tid >> 6;   // wave == one row of 64 px
    const int lq = tw >> 4;                   // lane quadrant 0..3
    const int lr = tw & 15;                   // lane 0..15 in quadrant
    const int bxp = blockIdx.x;        // 0..3
    const int byp = blockIdx.y;        // 0..31
    const int b   = blockIdx.z;        // 0..7
    const int w0 = bxp*TW + tw;
    const int h0 = byp*TH + th;
    const int pixoff = h0*IMG_W + w0;

    // edge-correction table + skip weights (bf16) -> LDS
    for (int i = tid; i < 576; i += 512) tbl[i] = table_g[i];
    for (int i = tid; i < 4096; i += 512)
        A_lds[(i >> 6)*72 + (i & 63)] = f2bf(skipw[i]);   // [o][c], stride 72

    const float* xb = x + (size_t)b * CIN * HW;
    unsigned short* xbf = &wbuf[th][0];   // [64 px][40] bf16 (one 32-cin chunk)
    float* tbuf = (float*)&wbuf[th][0];   // [64 px][20] f32  (reused after)

    // Phase A: per 32-cin chunk — load, pack sign bits, bf16 -> per-wave LDS,
    // then pull MFMA B-fragments into registers.
    bf16x8 B[4][2];
    unsigned int wbits[2];
    #pragma unroll
    for (int kk = 0; kk < 2; ++kk) {
        unsigned int wb = 0;
        #pragma unroll
        for (int j = 0; j < 32; ++j) {
            float xv = xb[(kk*32 + j)*HW + pixoff];
            unsigned int s = __float_as_uint(xv + mb[kk*32 + j]) >> 31;  // 1 iff neg
            wb |= s << j;
            xbf[tw*40 + j] = f2bf(xv);
        }
        wbits[kk] = wb;
        lds_fence();                     // same-wave writes complete before reads
        #pragma unroll
        for (int g = 0; g < 4; ++g)
            B[g][kk] = *(const bf16x8*)&xbf[(g*16 + lr)*40 + lq*8];
        lds_fence();                     // reads done before next chunk's writes
    }
    pack[th+1][tw+1] = ((unsigned long long)wbits[1] << 32) | wbits[0];

    // Phase A2: halo sign words. 148 halo pixels * 2 half-words = 296 jobs.
    if (tid < 296) {
        int j = tid >> 1, half = tid & 1;
        int rr, cc;
        if (j < 66)       { rr = 0;       cc = j;       }
        else if (j < 132) { rr = TH+1;    cc = j - 66;  }
        else if (j < 140) { rr = j - 131; cc = 0;       }   // rr = 1..8
        else              { rr = j - 139; cc = TW+1;    }   // rr = 1..8
        int hg = byp*TH + rr - 1;
        int wg = bxp*TW + cc - 1;
        unsigned int wword = 0u;
        if (hg >= 0 && hg < IMG_H && wg >= 0 && wg < IMG_W) {
            int po = hg*IMG_W + wg;
            #pragma unroll
            for (int k = 0; k < 32; ++k) {
                int c = half*32 + k;
                float xv = xb[c*HW + po];
                unsigned int u = __float_as_uint(xv + mb[c]) >> 31;
                wword |= u << k;
            }
        }
        ((unsigned int*)&pack[rr][cc])[half] = wword;   // little-endian halves
    }
    __syncthreads();

    const int pr  = (h0 == 0) ? 1 : ((h0 == IMG_H-1) ? 2 : 0);
    const int pcc = (w0 == 0) ? 1 : ((w0 == IMG_W-1) ? 2 : 0);
    const int pat = pr*3 + pcc;

    unsigned long long W[9];
    #pragma unroll
    for (int t = 0; t < 9; ++t) W[t] = pack[th + t/3][tw + t%3];

    float* outb = out + (size_t)b * COUT * HW;
    const int obase = h0*IMG_W + bxp*TW;

    // Main loop over output-channel chunks (16 couts per rt).
    for (int rt = 0; rt < 4; ++rt) {
        // A-fragments: skip_w[rt*16+lr][lq*8 + 0..7] and [32 + lq*8 + 0..7]
        bf16x8 A0 = *(const bf16x8*)&A_lds[(rt*16 + lr)*72 + lq*8];
        bf16x8 A1 = *(const bf16x8*)&A_lds[(rt*16 + lr)*72 + 32 + lq*8];
        f32x4 acc[4];
        #pragma unroll
        for (int g = 0; g < 4; ++g) {
            f32x4 a = {0.f, 0.f, 0.f, 0.f};
            a = __builtin_amdgcn_mfma_f32_16x16x32_bf16(A0, B[g][0], a, 0, 0, 0);
            a = __builtin_amdgcn_mfma_f32_16x16x32_bf16(A1, B[g][1], a, 0, 0, 0);
            acc[g] = a;
        }
        // popcount + RPReLU for o = rt*16 + q at this thread's own pixel
        #pragma unroll
        for (int q4 = 0; q4 < 4; ++q4) {
            f32x4 tq;
            #pragma unroll
            for (int qi = 0; qi < 4; ++qi) {
                const int o = rt*16 + q4*4 + qi;
                unsigned int S = 0;
                #pragma unroll
                for (int t = 0; t < 9; ++t)
                    S += (unsigned int)__popcll(W[t] ^ wwords[o*9 + t]);
                float tv = cA_g[o] - cS_g[o]*(float)S;
                if (pat) tv += tbl[o*9 + pat];       // border correction (rare)
                tv = fmaxf(tv, 0.f) + aP_g[o]*fminf(tv, 0.f);
                tq[qi] = tv + cB_g[o];
            }
            *(f32x4*)&tbuf[tw*20 + q4*4] = tq;
        }
        lds_fence();                     // tbuf writes complete before reads
        #pragma unroll
        for (int g = 0; g < 4; ++g) {
            f32x4 tv4 = *(const f32x4*)&tbuf[(g*16 + lr)*20 + lq*4];
            #pragma unroll
            for (int qi = 0; qi < 4; ++qi) {
                const int o = rt*16 + lq*4 + qi;
                outb[(size_t)o*HW + obase + g*16 + lr] = tv4[qi] + acc[g][qi];
            }
        }
        lds_fence();                     // reads done before next rt's writes
    }
}

extern "C" void kernel_launch(void* const* d_in, const int* in_sizes, int n_in,
                              void* d_out, int out_size, void* d_ws, size_t ws_size,
                              hipStream_t stream) {
    const float* x      = (const float*)d_in[0];
    const float* mb     = (const float*)d_in[1];
    const float* weight = (const float*)d_in[2];
    const float* pb0    = (const float*)d_in[3];
    const float* pw     = (const float*)d_in[4];
    const float* pb1    = (const float*)d_in[5];
    const float* skw    = (const float*)d_in[6];
    const float* skb    = (const float*)d_in[7];
    float* out = (float*)d_out;

    char* ws = (char*)d_ws;
    unsigned long long* wwords = (unsigned long long*)ws;   // 4608 B
    float* cA    = (float*)(ws + 4608);
    float* cS    = (float*)(ws + 4864);
    float* aP    = (float*)(ws + 5120);
    float* cB    = (float*)(ws + 5376);
    float* table = (float*)(ws + 5632);                      // 2304 B (total 7936)

    hipLaunchKernelGGL(bq_prep_kernel, dim3(1), dim3(576), 0, stream,
                       weight, pb0, pw, pb1, skb, wwords, cA, cS, aP, cB, table);
    hipLaunchKernelGGL(bq_main_kernel, dim3(4, 32, 8), dim3(512), 0, stream,
                       x, mb, skw, wwords, cA, cS, aP, cB, table, out);
}